// Round 7
// baseline (3783.981 us; speedup 1.0000x reference)
//
#include <hip/hip_runtime.h>

// CANPathIntegrator — MI355X round 7: A fully LDS-resident, 16-block groups,
// self-tagged relaxed-atomic mailbox (no acquire/release -> no cache inv).
// Grid 256 x 1024. Group g (32 batches) = blocks {s*16+g, s<16} (same XCD
// under bid%8 — heuristic only). Block s holds A cols [32s,32s+32) in LDS
// (pad 33), computes w rows for those cols each step; per-step cross-block
// coupling = 64 floats (sum_k g_k omega_k per batch/comp), exchanged as
// (tag<<32|f32bits) u64 words via RELAXED agent atomics: value is its own
// readiness flag -> one L3 RT, no fences, no invalidates. All blocks are
// co-resident (1 blk/CU via 145.9 KB dynamic LDS, grid == #CU) -> spin safe;
// SPIN_CAP bails (never hit when co-resident). Pure f32 math (= R2/R5).

namespace {
constexpr int NT = 128;
constexpr int ND = 512;
constexpr int NB_PER_G = 32;     // batches per group
constexpr int SPIN_CAP = 1 << 20;

// dynamic LDS layout (floats)
constexpr int L_AS   = 0;                   // As[512][33]
constexpr int L_ZXB  = L_AS  + 512 * 33;    // zxb[32][516]  batch-major
constexpr int L_WPZ  = L_ZXB + 32 * 516;    // wpz[2][32][36]
constexpr int L_GP   = L_WPZ + 2 * 32 * 36; // gp[8][64]
constexpr int L_DXS  = L_GP  + 8 * 64;      // dxs[64]
constexpr int L_DPIT = L_DXS + 64;          // dpit[64]
constexpr int L_XST  = L_DPIT + 64;         // xst[2][32][2]
constexpr int L_TOT  = L_XST + 2 * 32 * 2;  // 36480 floats = 145920 B
constexpr int DYN_BYTES = L_TOT * 4;
}

__global__ __launch_bounds__(1024) void can_main(
    const float* __restrict__ dx_pi, const float* __restrict__ z0,
    const float* __restrict__ x0, const float* __restrict__ omega,
    const float* __restrict__ A, const float* __restrict__ z0b,
    float* __restrict__ d_out, unsigned long long* __restrict__ pay)
{
    extern __shared__ float smem[];
    float* As   = smem + L_AS;
    float* zxb  = smem + L_ZXB;
    float* wpz  = smem + L_WPZ;
    float* gp   = smem + L_GP;
    float* dxs  = smem + L_DXS;
    float* dpit = smem + L_DPIT;
    float* xst  = smem + L_XST;

    const int tid = threadIdx.x;
    const int g = blockIdx.x & 15;     // group
    const int s = blockIdx.x >> 4;     // slot 0..15
    const int b0 = g * NB_PER_G;

    float* z_seq = d_out;
    float* x_seq = d_out + (size_t)512 * NT * ND;

    // ---- ||z0_base|| ----
    float sq = 0.f;
    if (tid < ND) { float f = z0b[tid]; sq = f * f; }
    #pragma unroll
    for (int o = 1; o < 64; o <<= 1) sq += __shfl_xor(sq, o, 64);
    if (tid < ND && (tid & 63) == 0) gp[tid >> 6] = sq;
    __syncthreads();
    float nsq = 0.f;
    #pragma unroll
    for (int w = 0; w < 8; ++w) nsq += gp[w];
    const float zinv = 1.0f / (sqrtf(nsq) + 1e-5f);
    __syncthreads();

    // ---- preload A slice: cols [32s, 32s+32), layout As[j][33] ----
    #pragma unroll 4
    for (int i = 0; i < 16; ++i) {
        int idx = i * 1024 + tid;           // 16384 elements
        int j = idx >> 5, c = idx & 31;
        As[j * 33 + c] = A[(size_t)j * 512 + 32 * s + c];
    }
    // xst[0] = x0
    if (tid < 32) {
        float2 x2 = reinterpret_cast<const float2*>(x0)[b0 + tid];
        xst[2 * tid] = x2.x; xst[2 * tid + 1] = x2.y;
    }
    // persistent per-thread state
    const int k = tid & 255, bg = tid >> 8;      // zx-gen: pair k, batch group bg
    float2 om2 = reinterpret_cast<const float2*>(omega)[k];
    const float om0 = om2.x, om1 = om2.y;
    float2 vv = reinterpret_cast<const float2*>(z0b)[k];
    const float v0 = vv.x * zinv, v1 = vv.y * zinv;
    float o3x = 0.f, o3y = 0.f;                  // stage-3 omega (tid<512)
    if (tid < 512) {
        float2 o2 = reinterpret_cast<const float2*>(omega)[16 * s + (tid >> 5)];
        o3x = o2.x; o3y = o2.y;
    }
    float zr00 = 0, zr01 = 0, zr10 = 0, zr11 = 0; // carry z, batches 2s,2s+1
    if (tid < 256) {
        float2 za = reinterpret_cast<const float2*>(z0)[(size_t)(b0 + 2 * s) * 256 + k];
        float2 zb = reinterpret_cast<const float2*>(z0)[(size_t)(b0 + 2 * s + 1) * 256 + k];
        zr00 = za.x; zr01 = za.y; zr10 = zb.x; zr11 = zb.y;
    }
    // zero wpz[0]
    for (int i = tid; i < 32 * 36; i += 1024) wpz[i] = 0.f;
    __syncthreads();

    // zxb(0): thread (k, bg) -> batches 8bg..8bg+7
    #pragma unroll
    for (int bi = 0; bi < 8; ++bi) {
        int b = 8 * bg + bi;
        float th = om0 * xst[2 * b] + om1 * xst[2 * b + 1];
        float sn, cs; __sincosf(th, &sn, &cs);
        zxb[b * 516 + 2 * k]     = cs * v0 - sn * v1;
        zxb[b * 516 + 2 * k + 1] = sn * v0 + cs * v1;
    }
    __syncthreads();

    for (int t = 0; t < NT; ++t) {
        const int pq = t & 1;
        const unsigned int tag = (unsigned int)(t + 1);

        // dpit(t) prefetch (latency hides under matvec)
        if (tid >= 992) {
            int b = tid - 992;
            float2 p2 = reinterpret_cast<const float2*>(dx_pi)[(size_t)(b0 + b) * NT + t];
            dpit[2 * b] = p2.x; dpit[2 * b + 1] = p2.y;
        }

        // ---- stage 2: matvec partials -> ds_add into wpz[pq] ----
        {
            const int cp = tid & 15, bq = (tid >> 4) & 3, jg = tid >> 6;
            const float* Ap = As + jg * 32 * 33 + 2 * cp;
            const float* Zb = zxb + (8 * bq) * 516 + jg * 32;
            float acc[2][8];
            #pragma unroll
            for (int c2 = 0; c2 < 2; ++c2)
                #pragma unroll
                for (int bi = 0; bi < 8; ++bi) acc[c2][bi] = 0.f;
            #pragma unroll 2
            for (int q = 0; q < 8; ++q) {
                float a00 = Ap[(4 * q + 0) * 33], a01 = Ap[(4 * q + 0) * 33 + 1];
                float a10 = Ap[(4 * q + 1) * 33], a11 = Ap[(4 * q + 1) * 33 + 1];
                float a20 = Ap[(4 * q + 2) * 33], a21 = Ap[(4 * q + 2) * 33 + 1];
                float a30 = Ap[(4 * q + 3) * 33], a31 = Ap[(4 * q + 3) * 33 + 1];
                #pragma unroll
                for (int bi = 0; bi < 8; ++bi) {
                    float4 z = *reinterpret_cast<const float4*>(&Zb[bi * 516 + 4 * q]);
                    acc[0][bi] += a00 * z.x + a10 * z.y + a20 * z.z + a30 * z.w;
                    acc[1][bi] += a01 * z.x + a11 * z.y + a21 * z.z + a31 * z.w;
                }
            }
            float* wp = wpz + pq * 1152;
            #pragma unroll
            for (int c2 = 0; c2 < 2; ++c2)
                #pragma unroll
                for (int bi = 0; bi < 8; ++bi)
                    atomicAdd(&wp[(2 * cp + c2) * 36 + 8 * bq + bi], acc[c2][bi]);
        }
        __syncthreads();  // B2

        // ---- stage 3 window: g_k partials | zero dxs | zero wpz[1-pq] ----
        if (tid < 512) {
            int kl = tid >> 5, b = tid & 31;
            const float* wp = wpz + pq * 1152;
            float we = wp[(2 * kl) * 36 + b];
            float wo = wp[(2 * kl + 1) * 36 + b];
            float zc0 = zxb[b * 516 + 32 * s + 2 * kl];
            float zc1 = zxb[b * 516 + 32 * s + 2 * kl + 1];
            float gk = wo * zc0 - we * zc1;
            float d0 = gk * o3x, d1 = gk * o3y;
            d0 += __shfl_xor(d0, 32, 64);       // combine the wave's kl pair
            d1 += __shfl_xor(d1, 32, 64);
            if ((tid & 63) < 32) {
                gp[(tid >> 6) * 64 + 2 * b]     = d0;
                gp[(tid >> 6) * 64 + 2 * b + 1] = d1;
            }
        } else if (tid < 576) {
            dxs[tid - 512] = 0.f;
        } else {
            float* wz = wpz + (1 - pq) * 1152;
            for (int i = tid - 576; i < 1152; i += 448) wz[i] = 0.f;
        }
        __syncthreads();  // B3

        // ---- publish + spin (self-tagged u64, relaxed agent atomics) ----
        const size_t mbase = (size_t)(g * 2 + pq) * 16;
        if (tid < 64) {
            float v = 0.f;
            #pragma unroll
            for (int w = 0; w < 8; ++w) v += gp[w * 64 + tid];
            unsigned long long u = ((unsigned long long)tag << 32) |
                                   (unsigned long long)__float_as_uint(v);
            __hip_atomic_store(&pay[(mbase + s) * 64 + tid], u,
                               __ATOMIC_RELAXED, __HIP_MEMORY_SCOPE_AGENT);
        }
        {
            int ss = tid >> 6, wi = tid & 63;
            unsigned long long* ap = &pay[(mbase + ss) * 64 + wi];
            unsigned long long v; int guard = 0;
            do {
                v = __hip_atomic_load(ap, __ATOMIC_RELAXED, __HIP_MEMORY_SCOPE_AGENT);
            } while ((unsigned int)(v >> 32) != tag && ++guard < SPIN_CAP);
            atomicAdd(&dxs[wi], __uint_as_float((unsigned int)v));
        }
        __syncthreads();  // B4

        // ---- stage 6: x update, zx(t+1), carry z + stores ----
        const float* xs = xst + pq * 64;
        float* xn = xst + (1 - pq) * 64;
        #pragma unroll
        for (int bi = 0; bi < 8; ++bi) {        // zx(t+1), thread (k,bg)
            int b = 8 * bg + bi;
            float dt0 = dpit[2 * b]     + 0.1f * dxs[2 * b];
            float dt1 = dpit[2 * b + 1] + 0.1f * dxs[2 * b + 1];
            float x0n = fminf(fmaxf(xs[2 * b]     + dt0, 0.f), 2.f);
            float x1n = fminf(fmaxf(xs[2 * b + 1] + dt1, 0.f), 2.f);
            float th = om0 * x0n + om1 * x1n;
            float sn, cs; __sincosf(th, &sn, &cs);
            zxb[b * 516 + 2 * k]     = cs * v0 - sn * v1;
            zxb[b * 516 + 2 * k + 1] = sn * v0 + cs * v1;
        }
        if (tid < 32) {                          // xst[1-pq]
            int b = tid;
            float dt0 = dpit[2 * b]     + 0.1f * dxs[2 * b];
            float dt1 = dpit[2 * b + 1] + 0.1f * dxs[2 * b + 1];
            xn[2 * b]     = fminf(fmaxf(xs[2 * b]     + dt0, 0.f), 2.f);
            xn[2 * b + 1] = fminf(fmaxf(xs[2 * b + 1] + dt1, 0.f), 2.f);
        }
        if (tid < 256) {                         // carry z for batches 2s,2s+1
            int ba = 2 * s, bb = 2 * s + 1;
            float dta0 = dpit[2 * ba]     + 0.1f * dxs[2 * ba];
            float dta1 = dpit[2 * ba + 1] + 0.1f * dxs[2 * ba + 1];
            float dtb0 = dpit[2 * bb]     + 0.1f * dxs[2 * bb];
            float dtb1 = dpit[2 * bb + 1] + 0.1f * dxs[2 * bb + 1];
            float sn, cs;
            __sincosf(om0 * dta0 + om1 * dta1, &sn, &cs);
            float n0 = cs * zr00 - sn * zr01, n1 = sn * zr00 + cs * zr01;
            zr00 = n0; zr01 = n1;
            __sincosf(om0 * dtb0 + om1 * dtb1, &sn, &cs);
            float m0 = cs * zr10 - sn * zr11, m1 = sn * zr10 + cs * zr11;
            zr10 = m0; zr11 = m1;
            reinterpret_cast<float2*>(z_seq)[((size_t)(b0 + ba) * NT + t) * 256 + k] =
                make_float2(n0, n1);
            reinterpret_cast<float2*>(z_seq)[((size_t)(b0 + bb) * NT + t) * 256 + k] =
                make_float2(m0, m1);
            if (tid == 0) {
                float xa0 = fminf(fmaxf(xs[2 * ba]     + dta0, 0.f), 2.f);
                float xa1 = fminf(fmaxf(xs[2 * ba + 1] + dta1, 0.f), 2.f);
                float xb0 = fminf(fmaxf(xs[2 * bb]     + dtb0, 0.f), 2.f);
                float xb1 = fminf(fmaxf(xs[2 * bb + 1] + dtb1, 0.f), 2.f);
                reinterpret_cast<float2*>(x_seq)[(size_t)(b0 + ba) * NT + t] =
                    make_float2(xa0, xa1);
                reinterpret_cast<float2*>(x_seq)[(size_t)(b0 + bb) * NT + t] =
                    make_float2(xb0, xb1);
            }
        }
        __syncthreads();  // B1'
    }
}

extern "C" void kernel_launch(void* const* d_in, const int* in_sizes, int n_in,
                              void* d_out, int out_size, void* d_ws, size_t ws_size,
                              hipStream_t stream) {
    (void)in_sizes; (void)n_in; (void)out_size; (void)ws_size;
    hipFuncSetAttribute(reinterpret_cast<const void*>(can_main),
                        hipFuncAttributeMaxDynamicSharedMemorySize, DYN_BYTES);
    hipLaunchKernelGGL(can_main, dim3(256), dim3(1024), DYN_BYTES, stream,
                       (const float*)d_in[0], (const float*)d_in[1],
                       (const float*)d_in[2], (const float*)d_in[3],
                       (const float*)d_in[4], (const float*)d_in[5],
                       (float*)d_out, (unsigned long long*)d_ws);
}